// Round 10
// baseline (224.784 us; speedup 1.0000x reference)
//
#include <hip/hip_runtime.h>
#include <hip/hip_bf16.h>

#define N_NODES 4096
#define BATCH 16
#define IN_CH 128
#define HID 8
#define HEADS 4
#define F1 (HEADS*HID)   // 32
#define OUT_CH 64
#define MAXD 64          // padded degree; true max ~51 (two drifting 5x5 windows + self)

// XCD-bijective swizzle for grid==4096: 8 XCDs x 512 contiguous nodes
__device__ __forceinline__ int node_swz(int bid) {
    return (bid & 7) * 512 + (bid >> 3);
}

// ---------------- graph build ----------------
__global__ void k_init(int* cursor) {
    int i = blockIdx.x * 256 + threadIdx.x;
    if (i < N_NODES) cursor[i] = 0;
}

__global__ void k_fill(const int* __restrict__ srcA, const int* __restrict__ dstA, int E,
                       int* cursor, int* nbrp) {
    int e = blockIdx.x * 256 + threadIdx.x;
    if (e < E) {
        int n = dstA[e];
        int pos = atomicAdd(&cursor[n], 1);
        nbrp[(n << 6) + pos] = srcA[e];
    }
}

// wl2[k] = dot(W2[k,:], al2);  wr2[k] = dot(W2[k,:], ar2)   (el2/er2 pulled into h-space)
__global__ void k_prep(const float* __restrict__ W2, const float* __restrict__ al2,
                       const float* __restrict__ ar2, float* __restrict__ wlr) {
    int t = threadIdx.x;     // 64 threads
    int k = t & 31;
    const float* a = (t < 32) ? al2 : ar2;
    float s = 0.f;
    #pragma unroll 8
    for (int c = 0; c < OUT_CH; c++) s += W2[k * OUT_CH + c] * a[c];
    wlr[((t < 32) ? 0 : 32) + k] = s;
}

// ---------------- Layer 1 projection -> feat1[n][b][32], el1/er1[n][b*4+h] ----------------
__global__ __launch_bounds__(256) void k_feat1(const float* __restrict__ x,
                                               const float* __restrict__ W1,
                                               const float* __restrict__ al1,
                                               const float* __restrict__ ar1,
                                               float* __restrict__ feat1,
                                               float* __restrict__ el1,
                                               float* __restrict__ er1) {
    __shared__ float lW1[IN_CH * F1];    // 16 KB
    __shared__ float lal[F1], lar[F1];
    __shared__ float lt[64 * 33];        // 8.25 KB transpose tile
    __shared__ float lel[64 * 4], ler[64 * 4];   // 2 KB
    int t = threadIdx.x;
    for (int i = t; i < IN_CH * F1; i += 256) lW1[i] = W1[i];
    if (t < F1) { lal[t] = al1[t]; lar[t] = ar1[t]; }
    __syncthreads();

    int b = blockIdx.y;
    int n0 = blockIdx.x * 64;
    int q = t >> 6;          // channel group == head == wave id
    int nl = t & 63;
    int n = n0 + nl;
    const float* xp = x + (size_t)b * (IN_CH * N_NODES) + n;
    const float* wq = lW1 + q * HID;

    float acc[HID];
    #pragma unroll
    for (int i = 0; i < HID; i++) acc[i] = 0.f;
    #pragma unroll 4
    for (int c = 0; c < IN_CH; c++) {
        float xv = xp[(size_t)c * N_NODES];          // 64-lane coalesced
        #pragma unroll
        for (int i = 0; i < HID; i++) acc[i] += xv * wq[c * F1 + i];   // LDS broadcast
    }

    float el = 0.f, er = 0.f;
    #pragma unroll
    for (int i = 0; i < HID; i++) {
        el += acc[i] * lal[q * HID + i];
        er += acc[i] * lar[q * HID + i];
    }
    lel[nl * 4 + q] = el;
    ler[nl * 4 + q] = er;

    #pragma unroll
    for (int i = 0; i < HID; i++) lt[nl * 33 + q * HID + i] = acc[i];
    __syncthreads();

    float* fp = feat1 + (size_t)n0 * (BATCH * F1) + b * F1;
    #pragma unroll
    for (int k = 0; k < 8; k++) {
        int idx = k * 256 + t;          // 64 nodes * 32 feats
        int nn = idx >> 5, f = idx & 31;
        fp[nn * (BATCH * F1) + f] = lt[nn * 33 + f];
    }
    if (t < 64) {
        ((float4*)el1)[(n0 + t) * BATCH + b] = *(float4*)&lel[t * 4];
        ((float4*)er1)[(n0 + t) * BATCH + b] = *(float4*)&ler[t * 4];
    }
}

// ---------------- Fused: layer-1 gather + mish -> h1; el2/er2 via wl2/wr2 ----------------
// Block per node. Static-unrolled phases (round-7 evidence: ILP > work reduction).
// feat2 is never materialized (projection commutes with the weighted sum).
__global__ __launch_bounds__(256) void k_gat1f(const float* __restrict__ feat1,
                                               const float* __restrict__ el1,
                                               const float* __restrict__ er1,
                                               const int* __restrict__ nbrp,
                                               const int* __restrict__ deg,
                                               const float* __restrict__ b1v,
                                               const float* __restrict__ wlr,
                                               float* __restrict__ h1,
                                               float* __restrict__ el2,
                                               float* __restrict__ er2) {
    __shared__ float lw[MAXD * 64];      // 16 KB: w[j][b*4+h]
    int t = threadIdx.x;
    int n = node_swz(blockIdx.x);
    int dg = deg[n];
    const int* nb = nbrp + (n << 6);

    // phase A: weights; j = 4r + (t>>6) wave-uniform; static j<32 + gated static j<64
    float ern = er1[(n << 6) + (t & 63)];
    #pragma unroll
    for (int r = 0; r < 8; r++) {
        int idx = r * 256 + t;
        int j = idx >> 6;
        int s = (j < dg) ? nb[j] : n;              // scalar select; always valid addr
        float e = el1[(s << 6) + (t & 63)] + ern;  // coalesced 256B per wave
        e = (e > 0.f) ? e : 0.2f * e;
        lw[idx] = (j < dg) ? __expf(e) : 0.f;
    }
    if (dg > 32) {
        #pragma unroll
        for (int r = 8; r < 16; r++) {
            int idx = r * 256 + t;
            int j = idx >> 6;
            int s = (j < dg) ? nb[j] : n;
            float e = el1[(s << 6) + (t & 63)] + ern;
            e = (e > 0.f) ? e : 0.2f * e;
            lw[idx] = (j < dg) ? __expf(e) : 0.f;
        }
    }
    __syncthreads();

    // phase B: gather; thread = (b = t>>4, c2 = t&15); 16 loads in flight per group
    int b = t >> 4, c2 = t & 15;
    int woff = (b << 2) + (c2 >> 2);
    int t2 = t << 1;
    float ax = 0.f, ay = 0.f, wsum = 0.f;
#define G1_EDGE(j) { \
        int s = ((j) < dg) ? nb[j] : n; \
        float w = lw[((j) << 6) + woff]; \
        wsum += w; \
        float2 f = *(const float2*)&feat1[(s << 9) + t2]; \
        ax += w * f.x; ay += w * f.y; }
    #pragma unroll
    for (int j = 0; j < 16; j++) G1_EDGE(j)
    if (dg > 16) {
        #pragma unroll
        for (int j = 16; j < 32; j++) G1_EDGE(j)
    }
    if (dg > 32) {
        #pragma unroll
        for (int j = 32; j < 48; j++) G1_EDGE(j)
    }
    if (dg > 48) {
        #pragma unroll
        for (int j = 48; j < 64; j++) G1_EDGE(j)
    }
#undef G1_EDGE

    float inv = 1.f / wsum;
    float2 bb = *(const float2*)&b1v[c2 * 2];
    float v0 = ax * inv + bb.x;
    float v1 = ay * inv + bb.y;
    // mish(v) = v * p/(p+2), p = t(t+2), t = e^v
    float e0 = __expf(v0), e1 = __expf(v1);
    float p0 = e0 * (e0 + 2.f), p1 = e1 * (e1 + 2.f);
    float o0 = v0 * p0 / (p0 + 2.f);
    float o1 = v1 * p1 / (p1 + 2.f);
    *(float2*)&h1[(n << 9) + t2] = make_float2(o0, o1);

    // el2/er2 = h . (W2 @ al2/ar2): partial dot + 16-lane reduce (b-groups stay in-wave)
    float2 l2 = *(const float2*)&wlr[c2 * 2];
    float2 r2 = *(const float2*)&wlr[32 + c2 * 2];
    float pl = o0 * l2.x + o1 * l2.y;
    float pr = o0 * r2.x + o1 * r2.y;
    #pragma unroll
    for (int off = 1; off < 16; off <<= 1) {
        pl += __shfl_xor(pl, off, 64);
        pr += __shfl_xor(pr, off, 64);
    }
    if (c2 == 0) { el2[(n << 4) + b] = pl; er2[(n << 4) + b] = pr; }
}

// ---------------- Layer 2: gather h1 (32-dim), project 32->64 in epilogue ----------------
__global__ __launch_bounds__(256) void k_gat2(const float* __restrict__ h1,
                                              const float* __restrict__ el2,
                                              const float* __restrict__ er2,
                                              const int* __restrict__ nbrp,
                                              const int* __restrict__ deg,
                                              const float* __restrict__ W2,
                                              const float* __restrict__ b2v,
                                              float* __restrict__ out2) {
    __shared__ float lw2[MAXD * BATCH];  // 4 KB: w[j][b]
    __shared__ float lagg[BATCH * 33];   // 2.1 KB padded: agg[b][k]
    int t = threadIdx.x;
    int n = node_swz(blockIdx.x);
    int dg = deg[n];
    const int* nb = nbrp + (n << 6);

    // phase A: weights; j = 16r + (t>>4); static j<32 + gated static j<64
    float ern = er2[(n << 4) + (t & 15)];
    #pragma unroll
    for (int r = 0; r < 2; r++) {
        int idx = r * 256 + t;
        int j = idx >> 4;
        int s = (j < dg) ? nb[j] : n;
        float e = el2[(s << 4) + (t & 15)] + ern;
        e = (e > 0.f) ? e : 0.2f * e;
        lw2[idx] = (j < dg) ? __expf(e) : 0.f;
    }
    if (dg > 32) {
        #pragma unroll
        for (int r = 2; r < 4; r++) {
            int idx = r * 256 + t;
            int j = idx >> 4;
            int s = (j < dg) ? nb[j] : n;
            float e = el2[(s << 4) + (t & 15)] + ern;
            e = (e > 0.f) ? e : 0.2f * e;
            lw2[idx] = (j < dg) ? __expf(e) : 0.f;
        }
    }
    __syncthreads();

    // phase B: gather h1 rows (2KB each); thread = (b, c2 float2 slot)
    int b = t >> 4, c2 = t & 15;
    int t2 = t << 1;
    float ax = 0.f, ay = 0.f, den = 0.f;
#define G2_EDGE(j) { \
        int s = ((j) < dg) ? nb[j] : n; \
        float w = lw2[((j) << 4) + b]; \
        den += w; \
        float2 f = *(const float2*)&h1[(s << 9) + t2]; \
        ax += w * f.x; ay += w * f.y; }
    #pragma unroll
    for (int j = 0; j < 16; j++) G2_EDGE(j)
    if (dg > 16) {
        #pragma unroll
        for (int j = 16; j < 32; j++) G2_EDGE(j)
    }
    if (dg > 32) {
        #pragma unroll
        for (int j = 32; j < 48; j++) G2_EDGE(j)
    }
    if (dg > 48) {
        #pragma unroll
        for (int j = 48; j < 64; j++) G2_EDGE(j)
    }
#undef G2_EDGE

    float inv = 1.f / den;
    lagg[b * 33 + c2 * 2]     = ax * inv;
    lagg[b * 33 + c2 * 2 + 1] = ay * inv;
    __syncthreads();

    // epilogue: out[n][b][c] = b2[c] + sum_k agg[b][k] * W2[k][c]; thread = (b, c4 = c2)
    float4 bb = *(const float4*)&b2v[c2 * 4];
    float4 acc = bb;
    const float* ag = &lagg[b * 33];
    #pragma unroll
    for (int k = 0; k < F1; k++) {
        float hk = ag[k];                               // bank (b+k)%32: conflict-free
        float4 w4 = *(const float4*)&W2[k * OUT_CH + c2 * 4];   // L1 broadcast
        acc.x += hk * w4.x; acc.y += hk * w4.y;
        acc.z += hk * w4.z; acc.w += hk * w4.w;
    }
    *(float4*)&out2[(n << 10) + (t << 2)] = acc;
}

// ---------------- transpose out2[n][b][c] -> out[b][c][n] ----------------
__global__ __launch_bounds__(256) void k_trans(const float* __restrict__ out2,
                                               float* __restrict__ out) {
    __shared__ float tile[64][65];
    int t = threadIdx.x;
    int b = blockIdx.y;
    int n0 = blockIdx.x * 64;
    int i = t >> 2;
    int c0 = (t & 3) * 4;
    #pragma unroll
    for (int p = 0; p < 4; p++) {
        int c = c0 + p * 16;
        float4 v = *(const float4*)&out2[(size_t)(n0 + i) * (BATCH * OUT_CH) + b * OUT_CH + c];
        tile[i][c] = v.x; tile[i][c + 1] = v.y; tile[i][c + 2] = v.z; tile[i][c + 3] = v.w;
    }
    __syncthreads();
    int nl = t & 63;
    int cw = t >> 6;
    #pragma unroll
    for (int q = 0; q < 16; q++) {
        int c = q * 4 + cw;
        out[(size_t)(b * OUT_CH + c) * N_NODES + n0 + nl] = tile[nl][c];
    }
}

extern "C" void kernel_launch(void* const* d_in, const int* in_sizes, int n_in,
                              void* d_out, int out_size, void* d_ws, size_t ws_size,
                              hipStream_t stream) {
    const float* x   = (const float*)d_in[0];
    const float* W1  = (const float*)d_in[1];
    const float* al1 = (const float*)d_in[2];
    const float* ar1 = (const float*)d_in[3];
    const float* b1v = (const float*)d_in[4];
    const float* W2  = (const float*)d_in[5];
    const float* al2 = (const float*)d_in[6];
    const float* ar2 = (const float*)d_in[7];
    const float* b2v = (const float*)d_in[8];
    const int* srcA  = (const int*)d_in[9];
    const int* dstA  = (const int*)d_in[10];
    int E = in_sizes[9];

    char* ws = (char*)d_ws;
    int*   cursor = (int*)(ws);                    // 16 KB; after k_fill == degree
    int*   nbrp   = (int*)(ws + 16384);            // 1 MB (slots >= deg garbage; selected out)
    float* feat1  = (float*)(ws + 1064960);        // 8.39 MB  [n][b][32]
    float* el1    = (float*)(ws + 9453568);        // 1.05 MB  [n][b*4+h]
    float* er1    = (float*)(ws + 10502144);       // 1.05 MB
    float* h1     = (float*)(ws + 19939328);       // 8.39 MB  [n][b][32]  (old feat2 slot)
    float* el2    = (float*)(ws + 36716544);       // 0.26 MB  [n][b]
    float* er2    = (float*)(ws + 36978688);       // 0.26 MB
    float* wlr    = (float*)(ws + 37240832);       // 256 B: wl2[32] ++ wr2[32]
    float* out2   = feat1;  // alias over feat1/el1/er1 (dead before k_gat2 writes out2)

    float* out = (float*)d_out;
    dim3 blk(256);

    k_init<<<dim3(16), blk, 0, stream>>>(cursor);
    k_fill<<<dim3((E + 255) / 256), blk, 0, stream>>>(srcA, dstA, E, cursor, nbrp);
    k_prep<<<dim3(1), dim3(64), 0, stream>>>(W2, al2, ar2, wlr);

    k_feat1<<<dim3(N_NODES / 64, BATCH), blk, 0, stream>>>(x, W1, al1, ar1, feat1, el1, er1);
    k_gat1f<<<dim3(N_NODES), blk, 0, stream>>>(feat1, el1, er1, nbrp, cursor, b1v, wlr,
                                               h1, el2, er2);

    k_gat2 <<<dim3(N_NODES), blk, 0, stream>>>(h1, el2, er2, nbrp, cursor, W2, b2v, out2);

    k_trans<<<dim3(N_NODES / 64, BATCH), blk, 0, stream>>>(out2, out);
}